// Round 1
// baseline (656.334 us; speedup 1.0000x reference)
//
#include <hip/hip_runtime.h>
#include <math.h>

// Problem constants (fixed by reference setup_inputs: B=4, T=1024, C=1024).
constexpr int B = 4, T = 1024, C = 1024, D = 1024;
constexpr int M = B * T;
constexpr int TILE = 64, BK = 16;
constexpr float K_CLAMP = 60.0f, K_EPS = 1e-8f;

__device__ __forceinline__ float epi(float v, int mode) {
    if (mode == 1) return expf(fminf(v, K_CLAMP));      // kc = exp(min(k,60))
    if (mode == 2) return 1.0f / (1.0f + expf(-v));     // sr = sigmoid(r)
    return v;                                           // v passthrough
}

// GEMM1: Y[b,d,t] = epi( sum_c (x[b,t,c]*tm[c] + x[b,t-1,c]*(1-tm[c])) * W[d,c] )
// Output stored TRANSPOSED [B,D,T] so the scan kernel reads contiguously.
// tx -> t (m-dir, 4/thread), ty -> d (n-dir, 4/thread): t-contiguous float4 stores.
__global__ __launch_bounds__(256) void gemm_mix_kernel(
    const float* __restrict__ x, const float* __restrict__ tm,
    const float* __restrict__ W, float* __restrict__ Yt, int mode)
{
    __shared__ float As[BK][TILE];   // [k][t]
    __shared__ float Bs[BK][TILE];   // [k][d]
    const int tid = threadIdx.x;
    const int tx = tid & 15;         // t-dir
    const int ty = tid >> 4;         // d-dir
    const int mtile = blockIdx.x * TILE;   // m = b*T + t (TILE divides T)
    const int ntile = blockIdx.y * TILE;   // d

    // staging roles: 64 rows x 4 float-groups
    const int lrow = tid >> 2;             // 0..63
    const int lcg = (tid & 3) << 2;        // 0,4,8,12

    const int mrow = mtile + lrow;
    const int tt = mrow & (T - 1);
    const float* xr = x + (size_t)mrow * C;
    const float* wr = W + (size_t)(ntile + lrow) * C;

    float acc[4][4];
#pragma unroll
    for (int i = 0; i < 4; i++)
#pragma unroll
        for (int j = 0; j < 4; j++) acc[i][j] = 0.f;

    for (int k0 = 0; k0 < C; k0 += BK) {
        float4 xv = *(const float4*)(xr + k0 + lcg);
        float4 xp;
        if (tt == 0) xp = make_float4(0.f, 0.f, 0.f, 0.f);
        else xp = *(const float4*)(xr - C + k0 + lcg);
        float4 tv = *(const float4*)(tm + k0 + lcg);
        float4 wv = *(const float4*)(wr + k0 + lcg);

        As[lcg + 0][lrow] = xv.x * tv.x + xp.x * (1.f - tv.x);
        As[lcg + 1][lrow] = xv.y * tv.y + xp.y * (1.f - tv.y);
        As[lcg + 2][lrow] = xv.z * tv.z + xp.z * (1.f - tv.z);
        As[lcg + 3][lrow] = xv.w * tv.w + xp.w * (1.f - tv.w);
        Bs[lcg + 0][lrow] = wv.x;
        Bs[lcg + 1][lrow] = wv.y;
        Bs[lcg + 2][lrow] = wv.z;
        Bs[lcg + 3][lrow] = wv.w;
        __syncthreads();
#pragma unroll
        for (int kk = 0; kk < BK; kk++) {
            float4 av = *(const float4*)&As[kk][tx << 2];
            float4 bv = *(const float4*)&Bs[kk][ty << 2];
            float a4[4] = {av.x, av.y, av.z, av.w};
            float b4[4] = {bv.x, bv.y, bv.z, bv.w};
#pragma unroll
            for (int i = 0; i < 4; i++)
#pragma unroll
                for (int j = 0; j < 4; j++)
                    acc[i][j] = fmaf(a4[i], b4[j], acc[i][j]);
        }
        __syncthreads();
    }

    const int bb = mtile >> 10;                     // mtile / T
    const int t0 = (mtile & (T - 1)) + (tx << 2);
#pragma unroll
    for (int j = 0; j < 4; j++) {
        const int d = ntile + (ty << 2) + j;
        float4 o;
        o.x = epi(acc[0][j], mode);
        o.y = epi(acc[1][j], mode);
        o.z = epi(acc[2][j], mode);
        o.w = epi(acc[3][j], mode);
        *(float4*)(Yt + (size_t)(bb * D + d) * T + t0) = o;
    }
}

// Scan: per (b,c) row of length T in [B,C,T] layout. One wave per row.
// a[t+1] = w*a[t] + kv[t]; wkv[t] = ef*kv[t] + a[t]; same for wk over kc.
// mid[b,c,t] = sr * wkv / (wk + eps)
__global__ __launch_bounds__(256) void scan_kernel(
    const float* __restrict__ kc, const float* __restrict__ vv,
    const float* __restrict__ sr, const float* __restrict__ td,
    const float* __restrict__ tf, float* __restrict__ mid)
{
    const int gtid = blockIdx.x * 256 + threadIdx.x;
    const int wave = gtid >> 6;            // 0..B*C-1
    const int lane = threadIdx.x & 63;
    const int c = wave & (C - 1);
    const int bidx = wave >> 10;           // wave / C
    const float wfac = expf(-expf(td[c]));
    const float ef = expf(tf[c]);
    const size_t base = ((size_t)(bidx * C + c)) * T + lane * 16;

    float kcl[16], vl[16], srl[16];
#pragma unroll
    for (int q = 0; q < 4; q++) {
        float4 a = *(const float4*)(kc + base + q * 4);
        float4 b2 = *(const float4*)(vv + base + q * 4);
        float4 c2 = *(const float4*)(sr + base + q * 4);
        kcl[q*4+0]=a.x; kcl[q*4+1]=a.y; kcl[q*4+2]=a.z; kcl[q*4+3]=a.w;
        vl [q*4+0]=b2.x; vl [q*4+1]=b2.y; vl [q*4+2]=b2.z; vl [q*4+3]=b2.w;
        srl[q*4+0]=c2.x; srl[q*4+1]=c2.y; srl[q*4+2]=c2.z; srl[q*4+3]=c2.w;
    }
    // lane-local inclusive scan summary (16 steps)
    float ua = 0.f, ub = 0.f;
#pragma unroll
    for (int i = 0; i < 16; i++) {
        float kv = kcl[i] * vl[i];
        ua = fmaf(wfac, ua, kv);
        ub = fmaf(wfac, ub, kcl[i]);
    }
    // Kogge-Stone wave scan with segment factor w^16 (channel-constant decay)
    float w2 = wfac * wfac, w4 = w2 * w2, w8 = w4 * w4, w16 = w8 * w8;
    float f = w16;
    float sa = ua, sb = ub;
#pragma unroll
    for (int off = 1; off < 64; off <<= 1) {
        float pa = __shfl_up(sa, off);
        float pb = __shfl_up(sb, off);
        if (lane >= off) { sa = fmaf(f, pa, sa); sb = fmaf(f, pb, sb); }
        f = f * f;
    }
    float a0 = __shfl_up(sa, 1);
    float b0 = __shfl_up(sb, 1);
    if (lane == 0) { a0 = 0.f; b0 = 0.f; }
    // replay with true prefix state
    float outl[16];
#pragma unroll
    for (int i = 0; i < 16; i++) {
        float kv = kcl[i] * vl[i];
        float wkv = fmaf(ef, kv, a0);
        float wk = fmaf(ef, kcl[i], b0) + K_EPS;
        outl[i] = srl[i] * (wkv / wk);
        a0 = fmaf(wfac, a0, kv);
        b0 = fmaf(wfac, b0, kcl[i]);
    }
#pragma unroll
    for (int q = 0; q < 4; q++) {
        float4 o = make_float4(outl[q*4+0], outl[q*4+1], outl[q*4+2], outl[q*4+3]);
        *(float4*)(mid + base + q * 4) = o;
    }
}

// GEMM2: out[b,t,d] = sum_c mid[b,c,t] * Wo[d,c]; A read transposed from [B,C,T].
// tx -> d (n-dir), ty -> t (m-dir): d-contiguous float4 stores (normal layout).
__global__ __launch_bounds__(256) void gemm_out_kernel(
    const float* __restrict__ Amid, const float* __restrict__ W,
    float* __restrict__ out)
{
    __shared__ float As[BK][TILE];   // [c][t]
    __shared__ float Bs[BK][TILE];   // [c][d]
    const int tid = threadIdx.x;
    const int tx = tid & 15;         // d-dir
    const int ty = tid >> 4;         // t-dir
    const int mtile = blockIdx.x * TILE;   // m = b*T + t
    const int ntile = blockIdx.y * TILE;   // d
    const int bb = mtile >> 10;
    const int tbase = mtile & (T - 1);

    const int acid = tid >> 4;             // c within tile 0..15
    const int at4 = (tid & 15) << 2;       // t offset 0..60

    const int lrow = tid >> 2;
    const int lcg = (tid & 3) << 2;
    const float* wr = W + (size_t)(ntile + lrow) * C;

    float acc[4][4];
#pragma unroll
    for (int i = 0; i < 4; i++)
#pragma unroll
        for (int j = 0; j < 4; j++) acc[i][j] = 0.f;

    for (int k0 = 0; k0 < C; k0 += BK) {
        float4 av = *(const float4*)(Amid + ((size_t)(bb * C + k0 + acid)) * T + tbase + at4);
        *(float4*)&As[acid][at4] = av;
        float4 wv = *(const float4*)(wr + k0 + lcg);
        Bs[lcg + 0][lrow] = wv.x;
        Bs[lcg + 1][lrow] = wv.y;
        Bs[lcg + 2][lrow] = wv.z;
        Bs[lcg + 3][lrow] = wv.w;
        __syncthreads();
#pragma unroll
        for (int kk = 0; kk < BK; kk++) {
            float4 a2 = *(const float4*)&As[kk][ty << 2];
            float4 b2 = *(const float4*)&Bs[kk][tx << 2];
            float a4[4] = {a2.x, a2.y, a2.z, a2.w};
            float b4[4] = {b2.x, b2.y, b2.z, b2.w};
#pragma unroll
            for (int i = 0; i < 4; i++)   // i = t
#pragma unroll
                for (int j = 0; j < 4; j++)   // j = d
                    acc[i][j] = fmaf(a4[i], b4[j], acc[i][j]);
        }
        __syncthreads();
    }
#pragma unroll
    for (int i = 0; i < 4; i++) {
        const int m = mtile + (ty << 2) + i;
        float4 o = make_float4(acc[i][0], acc[i][1], acc[i][2], acc[i][3]);
        *(float4*)(out + (size_t)m * D + ntile + (tx << 2)) = o;
    }
}

extern "C" void kernel_launch(void* const* d_in, const int* in_sizes, int n_in,
                              void* d_out, int out_size, void* d_ws, size_t ws_size,
                              hipStream_t stream) {
    const float* xq  = (const float*)d_in[0];
    // d_in[1]=xk, d_in[2]=xv unused by the reference module
    const float* td  = (const float*)d_in[3];
    const float* tf  = (const float*)d_in[4];
    const float* tmk = (const float*)d_in[5];
    const float* tmv = (const float*)d_in[6];
    const float* tmr = (const float*)d_in[7];
    const float* Wk  = (const float*)d_in[8];
    const float* Wv  = (const float*)d_in[9];
    const float* Wr  = (const float*)d_in[10];
    const float* Wo  = (const float*)d_in[11];
    float* out = (float*)d_out;

    const size_t BCT = (size_t)B * C * T;
    float* kc  = (float*)d_ws;
    float* vv  = kc + BCT;
    float* srb = vv + BCT;
    float* mid = srb + BCT;

    dim3 gg(M / TILE, D / TILE);   // 64 x 16
    dim3 bb(256);
    gemm_mix_kernel<<<gg, bb, 0, stream>>>(xq, tmk, Wk, kc, 1);
    gemm_mix_kernel<<<gg, bb, 0, stream>>>(xq, tmv, Wv, vv, 0);
    gemm_mix_kernel<<<gg, bb, 0, stream>>>(xq, tmr, Wr, srb, 2);
    scan_kernel<<<(B * C * 64) / 256, bb, 0, stream>>>(kc, vv, srb, td, tf, mid);
    gemm_out_kernel<<<gg, bb, 0, stream>>>(mid, Wo, out);
}

// Round 2
// 209.183 us; speedup vs baseline: 3.1376x; 3.1376x over previous
//
#include <hip/hip_runtime.h>
#include <math.h>

// B=4, T=1024, C=D=1024 fixed by reference setup_inputs.
constexpr int B = 4, T = 1024, C = 1024, D = 1024;
constexpr int M = B * T;
constexpr float K_CLAMP = 60.0f, K_EPS = 1e-8f;

typedef _Float16 half8 __attribute__((ext_vector_type(8)));
typedef _Float16 half4v __attribute__((ext_vector_type(4)));
typedef float float4v __attribute__((ext_vector_type(4)));

// ---- async global->LDS, 16B per lane. dst must be wave-uniform base; HW adds lane*16.
typedef __attribute__((address_space(3))) unsigned int lds_uint;
typedef const __attribute__((address_space(1))) unsigned int g_uint;
__device__ __forceinline__ void load_lds16(const void* g, void* l) {
    __builtin_amdgcn_global_load_lds((g_uint*)(size_t)g,
                                     (lds_uint*)(unsigned int)(size_t)l, 16, 0, 0);
}

// ============================================================================
// prep: ak/av/ar[m][c] = fp16( x[m][c]*tm[c] + x[m-1][c]*(1-tm[c]) ), xx[0]=0
// ============================================================================
__global__ __launch_bounds__(256) void prep_kernel(
    const float* __restrict__ x, const float* __restrict__ tmk,
    const float* __restrict__ tmv, const float* __restrict__ tmr,
    _Float16* __restrict__ ak, _Float16* __restrict__ av, _Float16* __restrict__ ar)
{
    const int gid = blockIdx.x * 256 + threadIdx.x;   // one 4-elem group
    const int m = gid >> 8;                           // C/4 = 256 groups/row
    const int cg = (gid & 255) << 2;
    const int t = m & (T - 1);
    float4 xv = *(const float4*)(x + (size_t)m * C + cg);
    float4 xp = make_float4(0.f, 0.f, 0.f, 0.f);
    if (t != 0) xp = *(const float4*)(x + (size_t)(m - 1) * C + cg);
    float4 k4 = *(const float4*)(tmk + cg);
    float4 v4 = *(const float4*)(tmv + cg);
    float4 r4 = *(const float4*)(tmr + cg);
    half4v ok, ov, orr;
    ok[0] = (_Float16)(xv.x * k4.x + xp.x * (1.f - k4.x));
    ok[1] = (_Float16)(xv.y * k4.y + xp.y * (1.f - k4.y));
    ok[2] = (_Float16)(xv.z * k4.z + xp.z * (1.f - k4.z));
    ok[3] = (_Float16)(xv.w * k4.w + xp.w * (1.f - k4.w));
    ov[0] = (_Float16)(xv.x * v4.x + xp.x * (1.f - v4.x));
    ov[1] = (_Float16)(xv.y * v4.y + xp.y * (1.f - v4.y));
    ov[2] = (_Float16)(xv.z * v4.z + xp.z * (1.f - v4.z));
    ov[3] = (_Float16)(xv.w * v4.w + xp.w * (1.f - v4.w));
    orr[0] = (_Float16)(xv.x * r4.x + xp.x * (1.f - r4.x));
    orr[1] = (_Float16)(xv.y * r4.y + xp.y * (1.f - r4.y));
    orr[2] = (_Float16)(xv.z * r4.z + xp.z * (1.f - r4.z));
    orr[3] = (_Float16)(xv.w * r4.w + xp.w * (1.f - r4.w));
    *(half4v*)(ak + (size_t)m * C + cg) = ok;
    *(half4v*)(av + (size_t)m * C + cg) = ov;
    *(half4v*)(ar + (size_t)m * C + cg) = orr;
}

// ============================================================================
// wcvt: fp32 [D][C] weights -> fp16 (B-operand layout: row d, k-contiguous)
// ============================================================================
__global__ __launch_bounds__(256) void wcvt_kernel(
    const float* __restrict__ w0, const float* __restrict__ w1,
    const float* __restrict__ w2, const float* __restrict__ w3,
    _Float16* __restrict__ h0, _Float16* __restrict__ h1,
    _Float16* __restrict__ h2, _Float16* __restrict__ h3)
{
    const int mat = blockIdx.y;
    const float* s = mat == 0 ? w0 : mat == 1 ? w1 : mat == 2 ? w2 : w3;
    _Float16* d = mat == 0 ? h0 : mat == 1 ? h1 : mat == 2 ? h2 : h3;
    const int gid = blockIdx.x * 256 + threadIdx.x;
    float4 v = *(const float4*)(s + (size_t)gid * 4);
    half4v o;
    o[0] = (_Float16)v.x; o[1] = (_Float16)v.y;
    o[2] = (_Float16)v.z; o[3] = (_Float16)v.w;
    *(half4v*)(d + (size_t)gid * 4) = o;
}

// ============================================================================
// GEMM core: 128x128 tile, BK=32 halfs, 4 waves of 64x64 (4x4 16x16x32 MFMAs).
// LDS tiles hold 16B chunks; chunk kc of row r lives at slot r*4 + ((kc + (r>>1))&3)
// (XOR swizzle -> 2-way (free) bank aliasing on ds_read_b128).
// A rows: k-contiguous stride C. W rows: k-contiguous stride C (W[d][c]).
// ============================================================================
__device__ __forceinline__ void gemm_core(
    const _Float16* __restrict__ A, const _Float16* __restrict__ W,
    _Float16* lA, _Float16* lB, float4v acc[4][4])
{
    const int tid = threadIdx.x, wave = tid >> 6, lane = tid & 63;
    const int quad = lane >> 4, l15 = lane & 15;
    const int wm = wave & 1, wn = wave >> 1;

    // staging: 512 slots per tile, 2 issues of 256 threads
    const int s0 = tid, s1 = 256 + tid;
    const int r0 = s0 >> 2, kc0 = ((s0 & 3) - (r0 >> 1)) & 3;
    const int r1 = s1 >> 2, kc1 = ((s1 & 3) - (r1 >> 1)) & 3;
    const _Float16* a0 = A + (size_t)r0 * C + kc0 * 8;
    const _Float16* a1 = A + (size_t)r1 * C + kc1 * 8;
    const _Float16* b0 = W + (size_t)r0 * C + kc0 * 8;
    const _Float16* b1 = W + (size_t)r1 * C + kc1 * 8;
    _Float16* dA0 = lA + (size_t)(wave * 64) * 8;         // wave-uniform bases
    _Float16* dA1 = lA + (size_t)(256 + wave * 64) * 8;
    _Float16* dB0 = lB + (size_t)(wave * 64) * 8;
    _Float16* dB1 = lB + (size_t)(256 + wave * 64) * 8;

    int aOff[4], bOff[4];
#pragma unroll
    for (int i = 0; i < 4; i++) {
        int mm = wm * 64 + i * 16 + l15;
        aOff[i] = (mm * 4 + ((quad + (mm >> 1)) & 3)) * 8;
        int nn = wn * 64 + i * 16 + l15;
        bOff[i] = (nn * 4 + ((quad + (nn >> 1)) & 3)) * 8;
    }

    for (int k0 = 0; k0 < C; k0 += 32) {
        load_lds16(a0, dA0);
        load_lds16(a1, dA1);
        load_lds16(b0, dB0);
        load_lds16(b1, dB1);
        a0 += 32; a1 += 32; b0 += 32; b1 += 32;
        __syncthreads();   // drains vmcnt -> staged data visible
        half8 af[4], bf[4];
#pragma unroll
        for (int i = 0; i < 4; i++) af[i] = *(const half8*)(lA + aOff[i]);
#pragma unroll
        for (int i = 0; i < 4; i++) bf[i] = *(const half8*)(lB + bOff[i]);
#pragma unroll
        for (int i = 0; i < 4; i++)
#pragma unroll
            for (int j = 0; j < 4; j++)
                acc[i][j] = __builtin_amdgcn_mfma_f32_16x16x32_f16(af[i], bf[j], acc[i][j], 0, 0, 0);
        __syncthreads();   // all waves done reading before next stage
    }
}

// gemm_in: fused k/v/r. grid (32, 24): mat = y>>3, ntile = (y&7)*128.
// Epilogue: mode per mat (exp-clamp / none / sigmoid), fp16 store TRANSPOSED [B,D,T].
__global__ __launch_bounds__(256) void gemm_in_kernel(
    const _Float16* __restrict__ ak, const _Float16* __restrict__ av, const _Float16* __restrict__ ar,
    const _Float16* __restrict__ wk, const _Float16* __restrict__ wv, const _Float16* __restrict__ wr,
    _Float16* __restrict__ kc, _Float16* __restrict__ vv, _Float16* __restrict__ sr)
{
    __shared__ _Float16 lA[128 * 32];
    __shared__ _Float16 lB[128 * 32];
    const int mat = blockIdx.y >> 3;
    const int ntile = (blockIdx.y & 7) * 128;
    const int mtile = blockIdx.x * 128;
    const _Float16* A = (mat == 0 ? ak : mat == 1 ? av : ar) + (size_t)mtile * C;
    const _Float16* W = (mat == 0 ? wk : mat == 1 ? wv : wr) + (size_t)ntile * C;
    _Float16* Y = mat == 0 ? kc : mat == 1 ? vv : sr;

    float4v acc[4][4] = {};
    gemm_core(A, W, lA, lB, acc);

    const int tid = threadIdx.x, wave = tid >> 6, lane = tid & 63;
    const int quad = lane >> 4, l15 = lane & 15;
    const int wm = wave & 1, wn = wave >> 1;
    const int bidx = mtile >> 10;
    const int tbase = (mtile & (T - 1)) + wm * 64;
#pragma unroll
    for (int i = 0; i < 4; i++) {
#pragma unroll
        for (int j = 0; j < 4; j++) {
            const int d = ntile + wn * 64 + j * 16 + l15;
            const int t0 = tbase + i * 16 + quad * 4;
            half4v o;
#pragma unroll
            for (int r = 0; r < 4; r++) {
                float v = acc[i][j][r];
                if (mat == 0) v = expf(fminf(v, K_CLAMP));
                else if (mat == 2) v = 1.0f / (1.0f + expf(-v));
                o[r] = (_Float16)v;
            }
            *(half4v*)(Y + (((size_t)(bidx * D + d)) << 10) + t0) = o;
        }
    }
}

// gemm_out: out[m][d] fp32 = midT[m][c] * Wo[d][c]. grid (32, 8).
__global__ __launch_bounds__(256) void gemm_out_kernel(
    const _Float16* __restrict__ midT, const _Float16* __restrict__ wo,
    float* __restrict__ out)
{
    __shared__ _Float16 lA[128 * 32];
    __shared__ _Float16 lB[128 * 32];
    const int mtile = blockIdx.x * 128;
    const int ntile = blockIdx.y * 128;
    float4v acc[4][4] = {};
    gemm_core(midT + (size_t)mtile * C, wo + (size_t)ntile * C, lA, lB, acc);

    const int tid = threadIdx.x, wave = tid >> 6, lane = tid & 63;
    const int quad = lane >> 4, l15 = lane & 15;
    const int wm = wave & 1, wn = wave >> 1;
#pragma unroll
    for (int i = 0; i < 4; i++) {
#pragma unroll
        for (int j = 0; j < 4; j++) {
            const int dcol = ntile + wn * 64 + j * 16 + l15;
#pragma unroll
            for (int r = 0; r < 4; r++) {
                const int m = mtile + wm * 64 + i * 16 + quad * 4 + r;
                out[(size_t)m * D + dcol] = acc[i][j][r];
            }
        }
    }
}

// ============================================================================
// scan: per (b,c) wave over T. kc/vv/sr fp16 [B,C,T] in; mid fp16 [B,C,T] out.
// a[t+1] = w*a[t] + kv[t]; wkv = ef*kv + a; wk = ef*kc + b; mid = sr*wkv/(wk+eps)
// ============================================================================
__global__ __launch_bounds__(256) void scan_kernel(
    const _Float16* __restrict__ kc, const _Float16* __restrict__ vv,
    const _Float16* __restrict__ sr, const float* __restrict__ td,
    const float* __restrict__ tf, _Float16* __restrict__ mid)
{
    const int gtid = blockIdx.x * 256 + threadIdx.x;
    const int wave = gtid >> 6;
    const int lane = threadIdx.x & 63;
    const int c = wave & (C - 1);
    const int bidx = wave >> 10;
    const float wfac = expf(-expf(td[c]));
    const float ef = expf(tf[c]);
    const size_t base = (((size_t)(bidx * C + c)) << 10) + lane * 16;

    half8 kA = *(const half8*)(kc + base), kB = *(const half8*)(kc + base + 8);
    half8 vA = *(const half8*)(vv + base), vB = *(const half8*)(vv + base + 8);
    half8 sA = *(const half8*)(sr + base), sB = *(const half8*)(sr + base + 8);
    float kcl[16], vl[16], srl[16];
#pragma unroll
    for (int i = 0; i < 8; i++) {
        kcl[i] = (float)kA[i]; kcl[8 + i] = (float)kB[i];
        vl[i]  = (float)vA[i]; vl[8 + i]  = (float)vB[i];
        srl[i] = (float)sA[i]; srl[8 + i] = (float)sB[i];
    }
    float ua = 0.f, ub = 0.f;
#pragma unroll
    for (int i = 0; i < 16; i++) {
        float kv = kcl[i] * vl[i];
        ua = fmaf(wfac, ua, kv);
        ub = fmaf(wfac, ub, kcl[i]);
    }
    float w2 = wfac * wfac, w4 = w2 * w2, w8 = w4 * w4, w16 = w8 * w8;
    float f = w16, sa = ua, sb = ub;
#pragma unroll
    for (int off = 1; off < 64; off <<= 1) {
        float pa = __shfl_up(sa, off);
        float pb = __shfl_up(sb, off);
        if (lane >= off) { sa = fmaf(f, pa, sa); sb = fmaf(f, pb, sb); }
        f = f * f;
    }
    float a0 = __shfl_up(sa, 1);
    float b0 = __shfl_up(sb, 1);
    if (lane == 0) { a0 = 0.f; b0 = 0.f; }
    half8 o0, o1;
#pragma unroll
    for (int i = 0; i < 16; i++) {
        float kv = kcl[i] * vl[i];
        float wkv = fmaf(ef, kv, a0);
        float wk = fmaf(ef, kcl[i], b0) + K_EPS;
        float o = srl[i] * (wkv / wk);
        if (i < 8) o0[i] = (_Float16)o; else o1[i - 8] = (_Float16)o;
        a0 = fmaf(wfac, a0, kv);
        b0 = fmaf(wfac, b0, kcl[i]);
    }
    *(half8*)(mid + base) = o0;
    *(half8*)(mid + base + 8) = o1;
}

// ============================================================================
// transpose: mid fp16 [B,C,T] -> midT fp16 [B,T,C]; 64x64 tiles via LDS.
// ============================================================================
__global__ __launch_bounds__(256) void transpose_kernel(
    const _Float16* __restrict__ mid, _Float16* __restrict__ midT)
{
    __shared__ _Float16 tile[64][72];
    const int b = blockIdx.z;
    const int ct = blockIdx.y * 64;
    const int tt = blockIdx.x * 64;
    const int tid = threadIdx.x;
#pragma unroll
    for (int it = 0; it < 2; it++) {
        const int cc = (tid >> 3) + it * 32;
        const int t8 = (tid & 7) * 8;
        half8 v = *(const half8*)(mid + (((size_t)(b * C + ct + cc)) << 10) + tt + t8);
#pragma unroll
        for (int j = 0; j < 8; j++) tile[t8 + j][cc] = v[j];
    }
    __syncthreads();
#pragma unroll
    for (int it = 0; it < 2; it++) {
        const int t = (tid >> 3) + it * 32;
        const int c8 = (tid & 7) * 8;
        half8 v;
#pragma unroll
        for (int j = 0; j < 8; j++) v[j] = tile[t][c8 + j];
        *(half8*)(midT + (((size_t)(b * T + tt + t)) << 10) + ct + c8) = v;
    }
}

extern "C" void kernel_launch(void* const* d_in, const int* in_sizes, int n_in,
                              void* d_out, int out_size, void* d_ws, size_t ws_size,
                              hipStream_t stream) {
    const float* xq  = (const float*)d_in[0];
    const float* td  = (const float*)d_in[3];
    const float* tf  = (const float*)d_in[4];
    const float* tmk = (const float*)d_in[5];
    const float* tmv = (const float*)d_in[6];
    const float* tmr = (const float*)d_in[7];
    const float* Wk  = (const float*)d_in[8];
    const float* Wv  = (const float*)d_in[9];
    const float* Wr  = (const float*)d_in[10];
    const float* Wo  = (const float*)d_in[11];
    float* out = (float*)d_out;

    const size_t MC = (size_t)M * C;           // 4.19M elems, 8 MB fp16
    char* ws = (char*)d_ws;
    _Float16* ak   = (_Float16*)(ws);
    _Float16* av   = (_Float16*)(ws + MC * 2);
    _Float16* ar   = (_Float16*)(ws + MC * 4);
    _Float16* wk16 = (_Float16*)(ws + MC * 6);
    _Float16* wv16 = wk16 + (size_t)D * C;
    _Float16* wr16 = wv16 + (size_t)D * C;
    _Float16* wo16 = wr16 + (size_t)D * C;
    _Float16* kc16 = (_Float16*)(ws + MC * 6 + (size_t)D * C * 8);
    _Float16* vv16 = kc16 + MC;
    _Float16* sr16 = vv16 + MC;
    _Float16* mid  = ak;   // ak dead after gemm_in
    _Float16* midT = av;   // av dead after gemm_in

    prep_kernel<<<dim3(M * C / 4 / 256), dim3(256), 0, stream>>>(
        xq, tmk, tmv, tmr, ak, av, ar);
    wcvt_kernel<<<dim3(D * C / 4 / 256, 4), dim3(256), 0, stream>>>(
        Wk, Wv, Wr, Wo, wk16, wv16, wr16, wo16);
    gemm_in_kernel<<<dim3(M / 128, 24), dim3(256), 0, stream>>>(
        ak, av, ar, wk16, wv16, wr16, kc16, vv16, sr16);
    scan_kernel<<<dim3(B * C * 64 / 256), dim3(256), 0, stream>>>(
        kc16, vv16, sr16, td, tf, mid);
    transpose_kernel<<<dim3(T / 64, C / 64, B), dim3(256), 0, stream>>>(
        mid, midT);
    gemm_out_kernel<<<dim3(M / 128, D / 128), dim3(256), 0, stream>>>(
        midT, wo16, out);
}

// Round 3
// 188.139 us; speedup vs baseline: 3.4886x; 1.1119x over previous
//
#include <hip/hip_runtime.h>
#include <math.h>

// B=4, T=1024, C=D=1024 fixed by reference setup_inputs.
constexpr int B = 4, T = 1024, C = 1024, D = 1024;
constexpr int M = B * T;
constexpr float K_CLAMP = 60.0f, K_EPS = 1e-8f;

typedef _Float16 half8 __attribute__((ext_vector_type(8)));
typedef _Float16 half4v __attribute__((ext_vector_type(4)));
typedef float float4v __attribute__((ext_vector_type(4)));

// async global->LDS, 16B/lane. LDS dst is wave-uniform base; HW adds lane*16.
typedef __attribute__((address_space(3))) unsigned int lds_uint;
typedef const __attribute__((address_space(1))) unsigned int g_uint;
__device__ __forceinline__ void load_lds16(const void* g, void* l) {
    __builtin_amdgcn_global_load_lds((g_uint*)(size_t)g,
                                     (lds_uint*)(unsigned int)(size_t)l, 16, 0, 0);
}

__device__ __forceinline__ float fast_sigmoid(float v) {
    return __builtin_amdgcn_rcpf(1.0f + __expf(-v));
}

// ============================================================================
// prep: ak/av/ar[m][c] = fp16( x[m][c]*tm[c] + x[m-1][c]*(1-tm[c]) ), xx[0]=0
// ============================================================================
__global__ __launch_bounds__(256) void prep_kernel(
    const float* __restrict__ x, const float* __restrict__ tmk,
    const float* __restrict__ tmv, const float* __restrict__ tmr,
    _Float16* __restrict__ ak, _Float16* __restrict__ av, _Float16* __restrict__ ar)
{
    const int gid = blockIdx.x * 256 + threadIdx.x;   // one 4-elem group
    const int m = gid >> 8;                           // C/4 = 256 groups/row
    const int cg = (gid & 255) << 2;
    const int t = m & (T - 1);
    float4 xv = *(const float4*)(x + (size_t)m * C + cg);
    float4 xp = make_float4(0.f, 0.f, 0.f, 0.f);
    if (t != 0) xp = *(const float4*)(x + (size_t)(m - 1) * C + cg);
    float4 k4 = *(const float4*)(tmk + cg);
    float4 v4 = *(const float4*)(tmv + cg);
    float4 r4 = *(const float4*)(tmr + cg);
    half4v ok, ov, orr;
    ok[0] = (_Float16)(xv.x * k4.x + xp.x * (1.f - k4.x));
    ok[1] = (_Float16)(xv.y * k4.y + xp.y * (1.f - k4.y));
    ok[2] = (_Float16)(xv.z * k4.z + xp.z * (1.f - k4.z));
    ok[3] = (_Float16)(xv.w * k4.w + xp.w * (1.f - k4.w));
    ov[0] = (_Float16)(xv.x * v4.x + xp.x * (1.f - v4.x));
    ov[1] = (_Float16)(xv.y * v4.y + xp.y * (1.f - v4.y));
    ov[2] = (_Float16)(xv.z * v4.z + xp.z * (1.f - v4.z));
    ov[3] = (_Float16)(xv.w * v4.w + xp.w * (1.f - v4.w));
    orr[0] = (_Float16)(xv.x * r4.x + xp.x * (1.f - r4.x));
    orr[1] = (_Float16)(xv.y * r4.y + xp.y * (1.f - r4.y));
    orr[2] = (_Float16)(xv.z * r4.z + xp.z * (1.f - r4.z));
    orr[3] = (_Float16)(xv.w * r4.w + xp.w * (1.f - r4.w));
    *(half4v*)(ak + (size_t)m * C + cg) = ok;
    *(half4v*)(av + (size_t)m * C + cg) = ov;
    *(half4v*)(ar + (size_t)m * C + cg) = orr;
}

// ============================================================================
// wcvt: fp32 [D][C] weights -> fp16
// ============================================================================
__global__ __launch_bounds__(256) void wcvt_kernel(
    const float* __restrict__ w0, const float* __restrict__ w1,
    const float* __restrict__ w2, const float* __restrict__ w3,
    _Float16* __restrict__ h0, _Float16* __restrict__ h1,
    _Float16* __restrict__ h2, _Float16* __restrict__ h3)
{
    const int mat = blockIdx.y;
    const float* s = mat == 0 ? w0 : mat == 1 ? w1 : mat == 2 ? w2 : w3;
    _Float16* d = mat == 0 ? h0 : mat == 1 ? h1 : mat == 2 ? h2 : h3;
    const int gid = blockIdx.x * 256 + threadIdx.x;
    float4 v = *(const float4*)(s + (size_t)gid * 4);
    half4v o;
    o[0] = (_Float16)v.x; o[1] = (_Float16)v.y;
    o[2] = (_Float16)v.z; o[3] = (_Float16)v.w;
    *(half4v*)(d + (size_t)gid * 4) = o;
}

// ============================================================================
// gemm_in: fused k/v/r. 128x128 tile, BK=64 halfs (full 128B lines per row).
// LDS row = 8 chunks of 16B; chunk c of row r at slot r*8 + ((c+r)&7)
// (rotation swizzle -> 2-way (free) bank aliasing on ds_read_b128).
// grid (32, 24): mat = y>>3, ntile = (y&7)*128.
// ============================================================================
__global__ __launch_bounds__(256) void gemm_in_kernel(
    const _Float16* __restrict__ ak, const _Float16* __restrict__ av, const _Float16* __restrict__ ar,
    const _Float16* __restrict__ wk, const _Float16* __restrict__ wv, const _Float16* __restrict__ wr,
    _Float16* __restrict__ kc, _Float16* __restrict__ vv, _Float16* __restrict__ sr)
{
    __shared__ _Float16 lA[128 * 64];   // 16 KB
    __shared__ _Float16 lB[128 * 64];   // 16 KB
    const int tid = threadIdx.x, wave = tid >> 6, lane = tid & 63;
    const int quad = lane >> 4, l15 = lane & 15;
    const int wm = wave & 1, wn = wave >> 1;
    const int mat = blockIdx.y >> 3;
    const int ntile = (blockIdx.y & 7) * 128;
    const int mtile = blockIdx.x * 128;
    const _Float16* A = (mat == 0 ? ak : mat == 1 ? av : ar) + (size_t)mtile * C;
    const _Float16* W = (mat == 0 ? wk : mat == 1 ? wv : wr) + (size_t)ntile * C;

    // staging source: slot g = issue*256 + tid; r = g>>3, o = g&7, chunk = (o-r)&7
    const int rS = tid >> 3, oS = tid & 7, cS = (oS - rS) & 7;
    const _Float16* pA = A + (size_t)rS * C + cS * 8;
    const _Float16* pB = W + (size_t)rS * C + cS * 8;

    // fragment LDS offsets (halfs): row mm, chunk ks*4+quad -> mm*64 + ((chunk+mm)&7)*8
    int aOff[4], bOff[4];
#pragma unroll
    for (int i = 0; i < 4; i++) {
        int mm = wm * 64 + i * 16 + l15;
        aOff[i] = mm * 64 + (((quad + mm) & 7) << 3);
        int nn = wn * 64 + i * 16 + l15;
        bOff[i] = nn * 64 + (((quad + nn) & 7) << 3);
    }

    float4v acc[4][4] = {};
    for (int it = 0; it < 16; it++) {        // 16 * 64 = K=1024
#pragma unroll
        for (int n = 0; n < 4; n++) {        // A: 1024 slots, B: 1024 slots
            load_lds16(pA + (size_t)n * 32 * C, lA + (n * 256 + wave * 64) * 8);
            load_lds16(pB + (size_t)n * 32 * C, lB + (n * 256 + wave * 64) * 8);
        }
        pA += 64; pB += 64;
        __syncthreads();
        half8 af[4], bf[4];
#pragma unroll
        for (int i = 0; i < 4; i++) af[i] = *(const half8*)(lA + aOff[i]);
#pragma unroll
        for (int j = 0; j < 4; j++) bf[j] = *(const half8*)(lB + bOff[j]);
#pragma unroll
        for (int i = 0; i < 4; i++)
#pragma unroll
            for (int j = 0; j < 4; j++)
                acc[i][j] = __builtin_amdgcn_mfma_f32_16x16x32_f16(af[i], bf[j], acc[i][j], 0, 0, 0);
#pragma unroll
        for (int i = 0; i < 4; i++) af[i] = *(const half8*)(lA + (aOff[i] ^ 32));
#pragma unroll
        for (int j = 0; j < 4; j++) bf[j] = *(const half8*)(lB + (bOff[j] ^ 32));
#pragma unroll
        for (int i = 0; i < 4; i++)
#pragma unroll
            for (int j = 0; j < 4; j++)
                acc[i][j] = __builtin_amdgcn_mfma_f32_16x16x32_f16(af[i], bf[j], acc[i][j], 0, 0, 0);
        __syncthreads();
    }

    // epilogue: per-mat activation, fp16 store TRANSPOSED [B,D,T]
    const int bidx = mtile >> 10;
    const int tbase = (mtile & (T - 1)) + wm * 64;
    _Float16* Y = mat == 0 ? kc : mat == 1 ? vv : sr;
#pragma unroll
    for (int i = 0; i < 4; i++) {
#pragma unroll
        for (int j = 0; j < 4; j++) {
            const int d = ntile + wn * 64 + j * 16 + l15;
            const int t0 = tbase + i * 16 + quad * 4;
            half4v o;
#pragma unroll
            for (int r = 0; r < 4; r++) {
                float v = acc[i][j][r];
                if (mat == 0) v = __expf(fminf(v, K_CLAMP));
                else if (mat == 2) v = fast_sigmoid(v);
                o[r] = (_Float16)v;
            }
            *(half4v*)(Y + (((size_t)(bidx * D + d)) << 10) + t0) = o;
        }
    }
}

// ============================================================================
// gemm_out: out[m][d] fp32 = midT[m][c] * Wo[d][c]. 64x128 tile, BK=64.
// grid (64, 8) = 512 blocks (2/CU). Wave covers 32m x 64n.
// ============================================================================
__global__ __launch_bounds__(256) void gemm_out_kernel(
    const _Float16* __restrict__ midT, const _Float16* __restrict__ wo,
    float* __restrict__ out)
{
    __shared__ _Float16 lA[64 * 64];     // 8 KB
    __shared__ _Float16 lB[128 * 64];    // 16 KB
    const int tid = threadIdx.x, wave = tid >> 6, lane = tid & 63;
    const int quad = lane >> 4, l15 = lane & 15;
    const int wm = wave & 1, wn = wave >> 1;
    const int mtile = blockIdx.x * 64;
    const int ntile = blockIdx.y * 128;
    const _Float16* A = midT + (size_t)mtile * C;
    const _Float16* W = wo + (size_t)ntile * C;

    const int rS = tid >> 3, oS = tid & 7, cS = (oS - rS) & 7;
    const _Float16* pA = A + (size_t)rS * C + cS * 8;
    const _Float16* pB = W + (size_t)rS * C + cS * 8;

    int aOff[2], bOff[4];
#pragma unroll
    for (int i = 0; i < 2; i++) {
        int mm = wm * 32 + i * 16 + l15;
        aOff[i] = mm * 64 + (((quad + mm) & 7) << 3);
    }
#pragma unroll
    for (int j = 0; j < 4; j++) {
        int nn = wn * 64 + j * 16 + l15;
        bOff[j] = nn * 64 + (((quad + nn) & 7) << 3);
    }

    float4v acc[2][4] = {};
    for (int it = 0; it < 16; it++) {
#pragma unroll
        for (int n = 0; n < 2; n++)          // A: 512 slots
            load_lds16(pA + (size_t)n * 32 * C, lA + (n * 256 + wave * 64) * 8);
#pragma unroll
        for (int n = 0; n < 4; n++)          // B: 1024 slots
            load_lds16(pB + (size_t)n * 32 * C, lB + (n * 256 + wave * 64) * 8);
        pA += 64; pB += 64;
        __syncthreads();
        half8 af[2], bf[4];
#pragma unroll
        for (int i = 0; i < 2; i++) af[i] = *(const half8*)(lA + aOff[i]);
#pragma unroll
        for (int j = 0; j < 4; j++) bf[j] = *(const half8*)(lB + bOff[j]);
#pragma unroll
        for (int i = 0; i < 2; i++)
#pragma unroll
            for (int j = 0; j < 4; j++)
                acc[i][j] = __builtin_amdgcn_mfma_f32_16x16x32_f16(af[i], bf[j], acc[i][j], 0, 0, 0);
#pragma unroll
        for (int i = 0; i < 2; i++) af[i] = *(const half8*)(lA + (aOff[i] ^ 32));
#pragma unroll
        for (int j = 0; j < 4; j++) bf[j] = *(const half8*)(lB + (bOff[j] ^ 32));
#pragma unroll
        for (int i = 0; i < 2; i++)
#pragma unroll
            for (int j = 0; j < 4; j++)
                acc[i][j] = __builtin_amdgcn_mfma_f32_16x16x32_f16(af[i], bf[j], acc[i][j], 0, 0, 0);
        __syncthreads();
    }
#pragma unroll
    for (int i = 0; i < 2; i++) {
#pragma unroll
        for (int j = 0; j < 4; j++) {
            const int dcol = ntile + wn * 64 + j * 16 + l15;
#pragma unroll
            for (int r = 0; r < 4; r++) {
                const int m = mtile + wm * 32 + i * 16 + quad * 4 + r;
                out[(size_t)m * D + dcol] = acc[i][j][r];
            }
        }
    }
}

// ============================================================================
// scan: per (b,c) wave over T. fp16 [B,C,T] in/out.
// ============================================================================
__global__ __launch_bounds__(256) void scan_kernel(
    const _Float16* __restrict__ kc, const _Float16* __restrict__ vv,
    const _Float16* __restrict__ sr, const float* __restrict__ td,
    const float* __restrict__ tf, _Float16* __restrict__ mid)
{
    const int gtid = blockIdx.x * 256 + threadIdx.x;
    const int wave = gtid >> 6;
    const int lane = threadIdx.x & 63;
    const int c = wave & (C - 1);
    const int bidx = wave >> 10;
    const float wfac = expf(-expf(td[c]));
    const float ef = expf(tf[c]);
    const size_t base = (((size_t)(bidx * C + c)) << 10) + lane * 16;

    half8 kA = *(const half8*)(kc + base), kB = *(const half8*)(kc + base + 8);
    half8 vA = *(const half8*)(vv + base), vB = *(const half8*)(vv + base + 8);
    half8 sA = *(const half8*)(sr + base), sB = *(const half8*)(sr + base + 8);
    float kcl[16], vl[16], srl[16];
#pragma unroll
    for (int i = 0; i < 8; i++) {
        kcl[i] = (float)kA[i]; kcl[8 + i] = (float)kB[i];
        vl[i]  = (float)vA[i]; vl[8 + i]  = (float)vB[i];
        srl[i] = (float)sA[i]; srl[8 + i] = (float)sB[i];
    }
    float ua = 0.f, ub = 0.f;
#pragma unroll
    for (int i = 0; i < 16; i++) {
        float kv = kcl[i] * vl[i];
        ua = fmaf(wfac, ua, kv);
        ub = fmaf(wfac, ub, kcl[i]);
    }
    float w2 = wfac * wfac, w4 = w2 * w2, w8 = w4 * w4, w16 = w8 * w8;
    float f = w16, sa = ua, sb = ub;
#pragma unroll
    for (int off = 1; off < 64; off <<= 1) {
        float pa = __shfl_up(sa, off);
        float pb = __shfl_up(sb, off);
        if (lane >= off) { sa = fmaf(f, pa, sa); sb = fmaf(f, pb, sb); }
        f = f * f;
    }
    float a0 = __shfl_up(sa, 1);
    float b0 = __shfl_up(sb, 1);
    if (lane == 0) { a0 = 0.f; b0 = 0.f; }
    half8 o0, o1;
#pragma unroll
    for (int i = 0; i < 16; i++) {
        float kv = kcl[i] * vl[i];
        float wkv = fmaf(ef, kv, a0);
        float wk = fmaf(ef, kcl[i], b0) + K_EPS;
        float o = srl[i] * (wkv / wk);
        if (i < 8) o0[i] = (_Float16)o; else o1[i - 8] = (_Float16)o;
        a0 = fmaf(wfac, a0, kv);
        b0 = fmaf(wfac, b0, kcl[i]);
    }
    *(half8*)(mid + base) = o0;
    *(half8*)(mid + base + 8) = o1;
}

// ============================================================================
// transpose: mid fp16 [B,C,T] -> midT fp16 [B,T,C]; 64x64 tiles via LDS.
// ============================================================================
__global__ __launch_bounds__(256) void transpose_kernel(
    const _Float16* __restrict__ mid, _Float16* __restrict__ midT)
{
    __shared__ _Float16 tile[64][72];
    const int b = blockIdx.z;
    const int ct = blockIdx.y * 64;
    const int tt = blockIdx.x * 64;
    const int tid = threadIdx.x;
#pragma unroll
    for (int it = 0; it < 2; it++) {
        const int cc = (tid >> 3) + it * 32;
        const int t8 = (tid & 7) * 8;
        half8 v = *(const half8*)(mid + (((size_t)(b * C + ct + cc)) << 10) + tt + t8);
#pragma unroll
        for (int j = 0; j < 8; j++) tile[t8 + j][cc] = v[j];
    }
    __syncthreads();
#pragma unroll
    for (int it = 0; it < 2; it++) {
        const int t = (tid >> 3) + it * 32;
        const int c8 = (tid & 7) * 8;
        half8 v;
#pragma unroll
        for (int j = 0; j < 8; j++) v[j] = tile[t][c8 + j];
        *(half8*)(midT + (((size_t)(b * T + tt + t)) << 10) + ct + c8) = v;
    }
}

extern "C" void kernel_launch(void* const* d_in, const int* in_sizes, int n_in,
                              void* d_out, int out_size, void* d_ws, size_t ws_size,
                              hipStream_t stream) {
    const float* xq  = (const float*)d_in[0];
    const float* td  = (const float*)d_in[3];
    const float* tf  = (const float*)d_in[4];
    const float* tmk = (const float*)d_in[5];
    const float* tmv = (const float*)d_in[6];
    const float* tmr = (const float*)d_in[7];
    const float* Wk  = (const float*)d_in[8];
    const float* Wv  = (const float*)d_in[9];
    const float* Wr  = (const float*)d_in[10];
    const float* Wo  = (const float*)d_in[11];
    float* out = (float*)d_out;

    const size_t MC = (size_t)M * C;
    char* ws = (char*)d_ws;
    _Float16* ak   = (_Float16*)(ws);
    _Float16* av   = (_Float16*)(ws + MC * 2);
    _Float16* ar   = (_Float16*)(ws + MC * 4);
    _Float16* wk16 = (_Float16*)(ws + MC * 6);
    _Float16* wv16 = wk16 + (size_t)D * C;
    _Float16* wr16 = wv16 + (size_t)D * C;
    _Float16* wo16 = wr16 + (size_t)D * C;
    _Float16* kc16 = (_Float16*)(ws + MC * 6 + (size_t)D * C * 8);
    _Float16* vv16 = kc16 + MC;
    _Float16* sr16 = vv16 + MC;
    _Float16* mid  = ak;   // ak dead after gemm_in
    _Float16* midT = av;   // av dead after gemm_in

    prep_kernel<<<dim3(M * C / 4 / 256), dim3(256), 0, stream>>>(
        xq, tmk, tmv, tmr, ak, av, ar);
    wcvt_kernel<<<dim3(D * C / 4 / 256, 4), dim3(256), 0, stream>>>(
        Wk, Wv, Wr, Wo, wk16, wv16, wr16, wo16);
    gemm_in_kernel<<<dim3(M / 128, 24), dim3(256), 0, stream>>>(
        ak, av, ar, wk16, wv16, wr16, kc16, vv16, sr16);
    scan_kernel<<<dim3(B * C * 64 / 256), dim3(256), 0, stream>>>(
        kc16, vv16, sr16, td, tf, mid);
    transpose_kernel<<<dim3(T / 64, C / 64, B), dim3(256), 0, stream>>>(
        mid, midT);
    gemm_out_kernel<<<dim3(M / 64, D / 128), dim3(256), 0, stream>>>(
        midT, wo16, out);
}

// Round 4
// 185.072 us; speedup vs baseline: 3.5464x; 1.0166x over previous
//
#include <hip/hip_runtime.h>
#include <math.h>

// B=4, T=1024, C=D=1024 fixed by reference setup_inputs.
constexpr int B = 4, T = 1024, C = 1024, D = 1024;
constexpr int M = B * T;
constexpr float K_CLAMP = 60.0f, K_EPS = 1e-8f;

typedef _Float16 half8 __attribute__((ext_vector_type(8)));
typedef _Float16 half4v __attribute__((ext_vector_type(4)));
typedef float float4v __attribute__((ext_vector_type(4)));

// async global->LDS, 16B/lane. LDS dst is wave-uniform base; HW adds lane*16.
typedef __attribute__((address_space(3))) unsigned int lds_uint;
typedef const __attribute__((address_space(1))) unsigned int g_uint;
__device__ __forceinline__ void load_lds16(const void* g, void* l) {
    __builtin_amdgcn_global_load_lds((g_uint*)(size_t)g,
                                     (lds_uint*)(unsigned int)(size_t)l, 16, 0, 0);
}

__device__ __forceinline__ float fast_sigmoid(float v) {
    return __builtin_amdgcn_rcpf(1.0f + __expf(-v));
}

// ============================================================================
// convert: fused prep (blocks 0..4095) + weight fp32->fp16 (blocks 4096..8191)
// prep: ak/av/ar[m][c] = fp16( x[m][c]*tm[c] + x[m-1][c]*(1-tm[c]) ), xx[0]=0
// ============================================================================
__global__ __launch_bounds__(256) void convert_kernel(
    const float* __restrict__ x, const float* __restrict__ tmk,
    const float* __restrict__ tmv, const float* __restrict__ tmr,
    _Float16* __restrict__ ak, _Float16* __restrict__ av, _Float16* __restrict__ ar,
    const float* __restrict__ w0, const float* __restrict__ w1,
    const float* __restrict__ w2, const float* __restrict__ w3,
    _Float16* __restrict__ h0, _Float16* __restrict__ h1,
    _Float16* __restrict__ h2, _Float16* __restrict__ h3)
{
    const int bid = blockIdx.x;
    if (bid < 4096) {
        const int gid = bid * 256 + threadIdx.x;
        const int m = gid >> 8;
        const int cg = (gid & 255) << 2;
        const int t = m & (T - 1);
        float4 xv = *(const float4*)(x + (size_t)m * C + cg);
        float4 xp = make_float4(0.f, 0.f, 0.f, 0.f);
        if (t != 0) xp = *(const float4*)(x + (size_t)(m - 1) * C + cg);
        float4 k4 = *(const float4*)(tmk + cg);
        float4 v4 = *(const float4*)(tmv + cg);
        float4 r4 = *(const float4*)(tmr + cg);
        half4v ok, ov, orr;
        ok[0] = (_Float16)(xv.x * k4.x + xp.x * (1.f - k4.x));
        ok[1] = (_Float16)(xv.y * k4.y + xp.y * (1.f - k4.y));
        ok[2] = (_Float16)(xv.z * k4.z + xp.z * (1.f - k4.z));
        ok[3] = (_Float16)(xv.w * k4.w + xp.w * (1.f - k4.w));
        ov[0] = (_Float16)(xv.x * v4.x + xp.x * (1.f - v4.x));
        ov[1] = (_Float16)(xv.y * v4.y + xp.y * (1.f - v4.y));
        ov[2] = (_Float16)(xv.z * v4.z + xp.z * (1.f - v4.z));
        ov[3] = (_Float16)(xv.w * v4.w + xp.w * (1.f - v4.w));
        orr[0] = (_Float16)(xv.x * r4.x + xp.x * (1.f - r4.x));
        orr[1] = (_Float16)(xv.y * r4.y + xp.y * (1.f - r4.y));
        orr[2] = (_Float16)(xv.z * r4.z + xp.z * (1.f - r4.z));
        orr[3] = (_Float16)(xv.w * r4.w + xp.w * (1.f - r4.w));
        *(half4v*)(ak + (size_t)m * C + cg) = ok;
        *(half4v*)(av + (size_t)m * C + cg) = ov;
        *(half4v*)(ar + (size_t)m * C + cg) = orr;
    } else {
        const int q = bid - 4096;
        const int mat = q >> 10;
        const float* s = mat == 0 ? w0 : mat == 1 ? w1 : mat == 2 ? w2 : w3;
        _Float16* d = mat == 0 ? h0 : mat == 1 ? h1 : mat == 2 ? h2 : h3;
        const int gid = (q & 1023) * 256 + threadIdx.x;
        float4 v = *(const float4*)(s + (size_t)gid * 4);
        half4v o;
        o[0] = (_Float16)v.x; o[1] = (_Float16)v.y;
        o[2] = (_Float16)v.z; o[3] = (_Float16)v.w;
        *(half4v*)(d + (size_t)gid * 4) = o;
    }
}

// ============================================================================
// gemm_in: fused k/v/r. 128x128 tile, BK=64 halfs (full 128B lines per row).
// LDS row = 8 chunks of 16B; chunk c of row r at slot r*8 + ((c+r)&7).
// Epilogue: activation, repack 128x128 fp16 tile in LDS, b128 row stores to
// [B,D,T]. grid (32, 24): mat = y>>3, ntile = (y&7)*128.
// ============================================================================
__global__ __launch_bounds__(256) void gemm_in_kernel(
    const _Float16* __restrict__ ak, const _Float16* __restrict__ av, const _Float16* __restrict__ ar,
    const _Float16* __restrict__ wk, const _Float16* __restrict__ wv, const _Float16* __restrict__ wr,
    _Float16* __restrict__ kc, _Float16* __restrict__ vv, _Float16* __restrict__ sr)
{
    __shared__ _Float16 lds[16896];     // 33792 B: K-loop uses 16384; repack 16896
    _Float16* lA = lds;                 // 128*64
    _Float16* lB = lds + 8192;          // 128*64
    const int tid = threadIdx.x, wave = tid >> 6, lane = tid & 63;
    const int quad = lane >> 4, l15 = lane & 15;
    const int wm = wave & 1, wn = wave >> 1;
    const int mat = blockIdx.y >> 3;
    const int ntile = (blockIdx.y & 7) * 128;
    const int mtile = blockIdx.x * 128;
    const _Float16* A = (mat == 0 ? ak : mat == 1 ? av : ar) + (size_t)mtile * C;
    const _Float16* W = (mat == 0 ? wk : mat == 1 ? wv : wr) + (size_t)ntile * C;

    const int rS = tid >> 3, oS = tid & 7, cS = (oS - rS) & 7;
    const _Float16* pA = A + (size_t)rS * C + cS * 8;
    const _Float16* pB = W + (size_t)rS * C + cS * 8;

    int aOff[4], bOff[4];
#pragma unroll
    for (int i = 0; i < 4; i++) {
        int mm = wm * 64 + i * 16 + l15;
        aOff[i] = mm * 64 + (((quad + mm) & 7) << 3);
        int nn = wn * 64 + i * 16 + l15;
        bOff[i] = nn * 64 + (((quad + nn) & 7) << 3);
    }

    float4v acc[4][4] = {};
    for (int it = 0; it < 16; it++) {        // 16 * 64 = K=1024
#pragma unroll
        for (int n = 0; n < 4; n++) {
            load_lds16(pA + (size_t)n * 32 * C, lA + (n * 256 + wave * 64) * 8);
            load_lds16(pB + (size_t)n * 32 * C, lB + (n * 256 + wave * 64) * 8);
        }
        pA += 64; pB += 64;
        __syncthreads();
        half8 af[4], bf[4];
#pragma unroll
        for (int i = 0; i < 4; i++) af[i] = *(const half8*)(lA + aOff[i]);
#pragma unroll
        for (int j = 0; j < 4; j++) bf[j] = *(const half8*)(lB + bOff[j]);
#pragma unroll
        for (int i = 0; i < 4; i++)
#pragma unroll
            for (int j = 0; j < 4; j++)
                acc[i][j] = __builtin_amdgcn_mfma_f32_16x16x32_f16(af[i], bf[j], acc[i][j], 0, 0, 0);
#pragma unroll
        for (int i = 0; i < 4; i++) af[i] = *(const half8*)(lA + (aOff[i] ^ 32));
#pragma unroll
        for (int j = 0; j < 4; j++) bf[j] = *(const half8*)(lB + (bOff[j] ^ 32));
#pragma unroll
        for (int i = 0; i < 4; i++)
#pragma unroll
            for (int j = 0; j < 4; j++)
                acc[i][j] = __builtin_amdgcn_mfma_f32_16x16x32_f16(af[i], bf[j], acc[i][j], 0, 0, 0);
        __syncthreads();
    }

    // epilogue: activation -> LDS repack (tile[d][t], pad 132) -> b128 stores
#pragma unroll
    for (int i = 0; i < 4; i++) {
#pragma unroll
        for (int j = 0; j < 4; j++) {
            const int dl = wn * 64 + j * 16 + l15;
            const int tl = wm * 64 + i * 16 + quad * 4;
            half4v o;
#pragma unroll
            for (int r = 0; r < 4; r++) {
                float v = acc[i][j][r];
                if (mat == 0) v = __expf(fminf(v, K_CLAMP));
                else if (mat == 2) v = fast_sigmoid(v);
                o[r] = (_Float16)v;
            }
            *(half4v*)(lds + dl * 132 + tl) = o;
        }
    }
    __syncthreads();
    const int bidx = mtile >> 10;
    const int tglob0 = mtile & (T - 1);
    _Float16* Y = mat == 0 ? kc : mat == 1 ? vv : sr;
#pragma unroll
    for (int s = 0; s < 8; s++) {
        const int cid = s * 256 + tid;        // 2048 chunks of 16B
        const int dl = cid >> 4, tc = (cid & 15) << 3;
        half8 v = *(const half8*)(lds + dl * 132 + tc);
        *(half8*)(Y + (((size_t)(bidx * D + ntile + dl)) << 10) + tglob0 + tc) = v;
    }
}

// ============================================================================
// gemm_out: out[m][d] fp32 = midT[m][c] * Wo[d][c]. 64x128 tile, BK=64.
// grid (64, 8) = 512 blocks. Epilogue repacks fp32 tile in LDS, float4 rows.
// ============================================================================
__global__ __launch_bounds__(256) void gemm_out_kernel(
    const _Float16* __restrict__ midT, const _Float16* __restrict__ wo,
    float* __restrict__ out)
{
    __shared__ __align__(16) char smem[33792];  // K-loop: 24576 B; repack: 64*132*4
    _Float16* lA = (_Float16*)smem;             // 64*64
    _Float16* lB = (_Float16*)(smem + 8192);    // 128*64
    float* tileo = (float*)smem;                // 64 x 132
    const int tid = threadIdx.x, wave = tid >> 6, lane = tid & 63;
    const int quad = lane >> 4, l15 = lane & 15;
    const int wm = wave & 1, wn = wave >> 1;
    const int mtile = blockIdx.x * 64;
    const int ntile = blockIdx.y * 128;
    const _Float16* A = midT + (size_t)mtile * C;
    const _Float16* W = wo + (size_t)ntile * C;

    const int rS = tid >> 3, oS = tid & 7, cS = (oS - rS) & 7;
    const _Float16* pA = A + (size_t)rS * C + cS * 8;
    const _Float16* pB = W + (size_t)rS * C + cS * 8;

    int aOff[2], bOff[4];
#pragma unroll
    for (int i = 0; i < 2; i++) {
        int mm = wm * 32 + i * 16 + l15;
        aOff[i] = mm * 64 + (((quad + mm) & 7) << 3);
    }
#pragma unroll
    for (int j = 0; j < 4; j++) {
        int nn = wn * 64 + j * 16 + l15;
        bOff[j] = nn * 64 + (((quad + nn) & 7) << 3);
    }

    float4v acc[2][4] = {};
    for (int it = 0; it < 16; it++) {
#pragma unroll
        for (int n = 0; n < 2; n++)
            load_lds16(pA + (size_t)n * 32 * C, lA + (n * 256 + wave * 64) * 8);
#pragma unroll
        for (int n = 0; n < 4; n++)
            load_lds16(pB + (size_t)n * 32 * C, lB + (n * 256 + wave * 64) * 8);
        pA += 64; pB += 64;
        __syncthreads();
        half8 af[2], bf[4];
#pragma unroll
        for (int i = 0; i < 2; i++) af[i] = *(const half8*)(lA + aOff[i]);
#pragma unroll
        for (int j = 0; j < 4; j++) bf[j] = *(const half8*)(lB + bOff[j]);
#pragma unroll
        for (int i = 0; i < 2; i++)
#pragma unroll
            for (int j = 0; j < 4; j++)
                acc[i][j] = __builtin_amdgcn_mfma_f32_16x16x32_f16(af[i], bf[j], acc[i][j], 0, 0, 0);
#pragma unroll
        for (int i = 0; i < 2; i++) af[i] = *(const half8*)(lA + (aOff[i] ^ 32));
#pragma unroll
        for (int j = 0; j < 4; j++) bf[j] = *(const half8*)(lB + (bOff[j] ^ 32));
#pragma unroll
        for (int i = 0; i < 2; i++)
#pragma unroll
            for (int j = 0; j < 4; j++)
                acc[i][j] = __builtin_amdgcn_mfma_f32_16x16x32_f16(af[i], bf[j], acc[i][j], 0, 0, 0);
        __syncthreads();
    }
    // repack fp32 tile [m][d] pad 132, then full-row float4 stores
#pragma unroll
    for (int i = 0; i < 2; i++) {
#pragma unroll
        for (int j = 0; j < 4; j++) {
            const int dl = wn * 64 + j * 16 + l15;
#pragma unroll
            for (int r = 0; r < 4; r++) {
                const int ml = wm * 32 + i * 16 + quad * 4 + r;
                tileo[ml * 132 + dl] = acc[i][j][r];
            }
        }
    }
    __syncthreads();
#pragma unroll
    for (int s = 0; s < 8; s++) {
        const int cid = s * 256 + tid;        // 2048 float4 chunks
        const int ml = cid >> 5, dc = (cid & 31) << 2;
        float4 v = *(const float4*)(tileo + ml * 132 + dc);
        *(float4*)(out + (size_t)(mtile + ml) * D + ntile + dc) = v;
    }
}

// ============================================================================
// scan_tr: fused scan + transpose. Block = 1024 threads = 16 waves = 16
// channels; wave scans its channel over T (16 t/lane), results transposed
// through LDS (pad 1026 -> conflict-free column gather), midT [B,T,C] out.
// ============================================================================
__global__ __launch_bounds__(1024) void scan_tr_kernel(
    const _Float16* __restrict__ kc, const _Float16* __restrict__ vv,
    const _Float16* __restrict__ sr, const float* __restrict__ td,
    const float* __restrict__ tf, _Float16* __restrict__ midT)
{
    __shared__ _Float16 L[16 * 1026];
    const int tid = threadIdx.x;
    const int w = tid >> 6, lane = tid & 63;
    const int bq = blockIdx.x >> 6;
    const int c0 = (blockIdx.x & 63) << 4;
    const int c = c0 + w;
    const float wfac = expf(-expf(td[c]));
    const float ef = expf(tf[c]);
    const size_t base = (((size_t)(bq * C + c)) << 10) + lane * 16;

    half8 kA = *(const half8*)(kc + base), kB = *(const half8*)(kc + base + 8);
    half8 vA = *(const half8*)(vv + base), vB = *(const half8*)(vv + base + 8);
    half8 sA = *(const half8*)(sr + base), sB = *(const half8*)(sr + base + 8);
    float kcl[16], vl[16], srl[16];
#pragma unroll
    for (int i = 0; i < 8; i++) {
        kcl[i] = (float)kA[i]; kcl[8 + i] = (float)kB[i];
        vl[i]  = (float)vA[i]; vl[8 + i]  = (float)vB[i];
        srl[i] = (float)sA[i]; srl[8 + i] = (float)sB[i];
    }
    float ua = 0.f, ub = 0.f;
#pragma unroll
    for (int i = 0; i < 16; i++) {
        float kv = kcl[i] * vl[i];
        ua = fmaf(wfac, ua, kv);
        ub = fmaf(wfac, ub, kcl[i]);
    }
    float w2 = wfac * wfac, w4 = w2 * w2, w8 = w4 * w4, w16 = w8 * w8;
    float f = w16, sa = ua, sb = ub;
#pragma unroll
    for (int off = 1; off < 64; off <<= 1) {
        float pa = __shfl_up(sa, off);
        float pb = __shfl_up(sb, off);
        if (lane >= off) { sa = fmaf(f, pa, sa); sb = fmaf(f, pb, sb); }
        f = f * f;
    }
    float a0 = __shfl_up(sa, 1);
    float b0 = __shfl_up(sb, 1);
    if (lane == 0) { a0 = 0.f; b0 = 0.f; }
    half8 o0, o1;
#pragma unroll
    for (int i = 0; i < 16; i++) {
        float kv = kcl[i] * vl[i];
        float wkv = fmaf(ef, kv, a0);
        float wk = fmaf(ef, kcl[i], b0) + K_EPS;
        float o = srl[i] * (wkv / wk);
        if (i < 8) o0[i] = (_Float16)o; else o1[i - 8] = (_Float16)o;
        a0 = fmaf(wfac, a0, kv);
        b0 = fmaf(wfac, b0, kcl[i]);
    }
    *(half8*)(L + w * 1026 + lane * 16) = o0;
    *(half8*)(L + w * 1026 + lane * 16 + 8) = o1;
    __syncthreads();
    // gather: thread t collects 16 channels, stores 32 B to midT[b][t][c0..]
    half8 g0, g1;
#pragma unroll
    for (int cc = 0; cc < 8; cc++)  g0[cc] = L[cc * 1026 + tid];
#pragma unroll
    for (int cc = 0; cc < 8; cc++)  g1[cc] = L[(cc + 8) * 1026 + tid];
    _Float16* dst = midT + (((size_t)(bq * T + tid)) << 10) + c0;
    *(half8*)(dst) = g0;
    *(half8*)(dst + 8) = g1;
}

extern "C" void kernel_launch(void* const* d_in, const int* in_sizes, int n_in,
                              void* d_out, int out_size, void* d_ws, size_t ws_size,
                              hipStream_t stream) {
    const float* xq  = (const float*)d_in[0];
    const float* td  = (const float*)d_in[3];
    const float* tf  = (const float*)d_in[4];
    const float* tmk = (const float*)d_in[5];
    const float* tmv = (const float*)d_in[6];
    const float* tmr = (const float*)d_in[7];
    const float* Wk  = (const float*)d_in[8];
    const float* Wv  = (const float*)d_in[9];
    const float* Wr  = (const float*)d_in[10];
    const float* Wo  = (const float*)d_in[11];
    float* out = (float*)d_out;

    const size_t MC = (size_t)M * C;
    char* ws = (char*)d_ws;
    _Float16* ak   = (_Float16*)(ws);
    _Float16* av   = (_Float16*)(ws + MC * 2);
    _Float16* ar   = (_Float16*)(ws + MC * 4);
    _Float16* wk16 = (_Float16*)(ws + MC * 6);
    _Float16* wv16 = wk16 + (size_t)D * C;
    _Float16* wr16 = wv16 + (size_t)D * C;
    _Float16* wo16 = wr16 + (size_t)D * C;
    _Float16* kc16 = (_Float16*)(ws + MC * 6 + (size_t)D * C * 8);
    _Float16* vv16 = kc16 + MC;
    _Float16* sr16 = vv16 + MC;
    _Float16* midT = ak;   // ak dead after gemm_in

    convert_kernel<<<dim3(8192), dim3(256), 0, stream>>>(
        xq, tmk, tmv, tmr, ak, av, ar, Wk, Wv, Wr, Wo, wk16, wv16, wr16, wo16);
    gemm_in_kernel<<<dim3(M / 128, 24), dim3(256), 0, stream>>>(
        ak, av, ar, wk16, wv16, wr16, kc16, vv16, sr16);
    scan_tr_kernel<<<dim3(B * C / 16), dim3(1024), 0, stream>>>(
        kc16, vv16, sr16, td, tf, midT);
    gemm_out_kernel<<<dim3(M / 64, D / 128), dim3(256), 0, stream>>>(
        midT, wo16, out);
}